// Round 1
// baseline (4502.984 us; speedup 1.0000x reference)
//
#include <hip/hip_runtime.h>
#include <hip/hip_bf16.h>
#include <math.h>

// Problem constants
#define B 64
#define S 64
#define T 21
#define ENC_D 512
#define HID 512
#define EMB 512
#define STYLE 128
#define VOCAB 32000

// ---------------------------------------------------------------------------
// Kernel A: h0 = concat(encode_hidden, style_emb[:,3,:]) @ W_e2d_w.T + b ; c0=0
// grid(64), block(256)
// ---------------------------------------------------------------------------
__global__ void h0_kernel(const float* __restrict__ enc_h,
                          const float* __restrict__ style,
                          const float* __restrict__ W,
                          const float* __restrict__ bias,
                          float* __restrict__ h, float* __restrict__ c) {
    int b = blockIdx.x;
    int tid = threadIdx.x;
    __shared__ __attribute__((aligned(16))) float in[640];
    for (int i = tid; i < 512; i += 256) in[i] = enc_h[b * 512 + i];
    if (tid < 128) in[512 + tid] = style[b * 512 + 384 + tid];  // style[b][3][tid]
    __syncthreads();
    for (int j = tid; j < 512; j += 256) {
        const float4* w4 = (const float4*)(W + (size_t)j * 640);
        float acc = 0.f;
#pragma unroll 4
        for (int k4 = 0; k4 < 160; k4++) {
            float4 w = w4[k4];
            float4 iv = *(const float4*)(in + k4 * 4);
            acc += w.x * iv.x + w.y * iv.y + w.z * iv.z + w.w * iv.w;
        }
        h[b * 512 + j] = acc + bias[j];
        c[b * 512 + j] = 0.f;
    }
}

// ---------------------------------------------------------------------------
// Kernel B: attention for one step. a = h@attn_W ; scores = enc_out · a ;
// softmax ; ctx = attn @ enc_out.   grid(64) = per batch row, block(256)
// ---------------------------------------------------------------------------
__global__ void attn_kernel(const float* __restrict__ h,
                            const float* __restrict__ attn_W,
                            const float* __restrict__ enc_out,
                            float* __restrict__ ctx) {
    int b = blockIdx.x;
    int tid = threadIdx.x;
    __shared__ __attribute__((aligned(16))) float hbuf[512];
    __shared__ __attribute__((aligned(16))) float abuf[512];
    __shared__ float scp[4][64];
    __shared__ float sc[64];

    for (int i = tid; i < 512; i += 256) hbuf[i] = h[b * 512 + i];
    __syncthreads();

    // a[d] = sum_j hbuf[j] * attn_W[j*512 + d]   (coalesced over d)
    {
        int d0 = tid, d1 = tid + 256;
        float acc0 = 0.f, acc1 = 0.f;
#pragma unroll 4
        for (int j = 0; j < 512; j++) {
            float hv = hbuf[j];
            acc0 += hv * attn_W[(size_t)j * 512 + d0];
            acc1 += hv * attn_W[(size_t)j * 512 + d1];
        }
        abuf[d0] = acc0;
        abuf[d1] = acc1;
    }
    __syncthreads();

    // scores partials: thread (s = tid&63, q = tid>>6) covers d in [q*128, q*128+128)
    {
        int s = tid & 63, q = tid >> 6;
        const float4* e4 = (const float4*)(enc_out + ((size_t)b * 64 + s) * 512 + q * 128);
        const float4* a4 = (const float4*)(abuf + q * 128);
        float acc = 0.f;
#pragma unroll 8
        for (int k = 0; k < 32; k++) {
            float4 e = e4[k];
            float4 a = a4[k];
            acc += e.x * a.x + e.y * a.y + e.z * a.z + e.w * a.w;
        }
        scp[q][s] = acc;
    }
    __syncthreads();

    // softmax over 64 scores in wave 0
    if (tid < 64) {
        float v = scp[0][tid] + scp[1][tid] + scp[2][tid] + scp[3][tid];
        float m = v;
        for (int off = 32; off > 0; off >>= 1) m = fmaxf(m, __shfl_xor(m, off, 64));
        float e = __expf(v - m);
        float ssum = e;
        for (int off = 32; off > 0; off >>= 1) ssum += __shfl_xor(ssum, off, 64);
        sc[tid] = e / ssum;
    }
    __syncthreads();

    // ctx[d] = sum_s attn[s] * enc_out[b][s][d]   (coalesced over d)
    {
        int d0 = tid, d1 = tid + 256;
        float acc0 = 0.f, acc1 = 0.f;
        const float* ep = enc_out + (size_t)b * 64 * 512;
#pragma unroll 4
        for (int s = 0; s < 64; s++) {
            float a = sc[s];
            acc0 += a * ep[(size_t)s * 512 + d0];
            acc1 += a * ep[(size_t)s * 512 + d1];
        }
        ctx[b * 512 + d0] = acc0;
        ctx[b * 512 + d1] = acc1;
    }
}

// ---------------------------------------------------------------------------
// Kernel C: gates partial GEMM. gates[b][j] = [ctx|emb] @ w_ih.T + h @ w_hh.T
// K = 1536 split as 3 segments x 2 halves (256 each). 64 j-tiles of 32.
// grid(64*6), block(256): lanes = b (weight rows wave-uniform -> broadcast).
// Output: part[chunk][j][b] (coalesced stores over b).
// ---------------------------------------------------------------------------
__global__ void gates_kernel(const float* __restrict__ ctx,
                             const float* __restrict__ h,
                             const float* __restrict__ emb_table,
                             const int* __restrict__ dec_in,
                             const float* __restrict__ w_ih,
                             const float* __restrict__ w_hh,
                             float* __restrict__ part, int t) {
    int jt = blockIdx.x & 63;
    int chunk = blockIdx.x >> 6;  // 0..5
    int seg = chunk >> 1;         // 0: ctx, 1: emb, 2: h
    int half = chunk & 1;         // k offset 0 / 256
    int tid = threadIdx.x;
    int b = tid & 63;
    int ty = tid >> 6;
    int j0 = jt * 32 + ty * 8;

    const float* src;
    if (seg == 0)      src = ctx + b * 512 + half * 256;
    else if (seg == 1) src = emb_table + (size_t)dec_in[b * T + t] * 512 + half * 256;
    else               src = h + b * 512 + half * 256;

    const float* wbase;
    size_t wstride;
    if (seg < 2) { wbase = w_ih + seg * 512 + half * 256; wstride = 1024; }
    else         { wbase = w_hh + half * 256;             wstride = 512; }

    float acc[8] = {0, 0, 0, 0, 0, 0, 0, 0};
    const float4* s4 = (const float4*)src;
#pragma unroll 4
    for (int k4 = 0; k4 < 64; k4++) {
        float4 iv = s4[k4];
#pragma unroll
        for (int jj = 0; jj < 8; jj++) {
            float4 w = *(const float4*)(wbase + (size_t)(j0 + jj) * wstride + k4 * 4);
            acc[jj] += w.x * iv.x + w.y * iv.y + w.z * iv.z + w.w * iv.w;
        }
    }
#pragma unroll
    for (int jj = 0; jj < 8; jj++) {
        part[((size_t)chunk * 2048 + (j0 + jj)) * 64 + b] = acc[jj];
    }
}

// ---------------------------------------------------------------------------
// Kernel D: reduce 6 partials, apply LSTM cell, write h, c, hseq[b][t][:]
// grid(128), block(256)
// ---------------------------------------------------------------------------
__global__ void lstm_update_kernel(const float* __restrict__ part,
                                   const float* __restrict__ b_ih,
                                   const float* __restrict__ b_hh,
                                   float* __restrict__ h, float* __restrict__ c,
                                   float* __restrict__ hseq, int t) {
    int g = blockIdx.x * 256 + threadIdx.x;  // 0..32767
    int b = g & 63;
    int u = g >> 6;  // 0..511
    float gate[4];
#pragma unroll
    for (int gi = 0; gi < 4; gi++) {
        int j = u + gi * 512;
        float s = b_ih[j] + b_hh[j];
#pragma unroll
        for (int cc = 0; cc < 6; cc++) s += part[((size_t)cc * 2048 + j) * 64 + b];
        gate[gi] = s;
    }
    float ig = 1.f / (1.f + __expf(-gate[0]));
    float fg = 1.f / (1.f + __expf(-gate[1]));
    float gg = tanhf(gate[2]);
    float og = 1.f / (1.f + __expf(-gate[3]));
    float cn = fg * c[b * 512 + u] + ig * gg;
    float hn = og * tanhf(cn);
    c[b * 512 + u] = cn;
    h[b * 512 + u] = hn;
    hseq[((size_t)b * T + t) * 512 + u] = hn;
}

// ---------------------------------------------------------------------------
// Kernel P1: row-wise sum of exp(logits) without materializing logits.
// Logits are tiny (|logit| <~ 2) so no max-subtraction needed.
// grid(500, 21): 64-vocab x 64-row tiles. block(256) = 16 vx-lanes x 16 row-groups.
// Each thread: 4 vocab x 4 rows register tile, K staged in LDS.
// ---------------------------------------------------------------------------
__global__ void proj_sumexp_kernel(const float* __restrict__ hseq,
                                   const float* __restrict__ proj_w,
                                   const float* __restrict__ proj_b,
                                   float* __restrict__ sumexp) {
    int r0 = blockIdx.y * 64;
    int v0 = blockIdx.x * 64;
    int tid = threadIdx.x;
    int vx = tid & 15, ry = tid >> 4;
    __shared__ __attribute__((aligned(16))) float4 in_lds[64 * 17];  // stride 17 f4: kills bank conflicts
    float acc[4][4] = {};
    int vbase = v0 + vx * 4;
    const float4* w4 = (const float4*)proj_w;

    for (int kc = 0; kc < 8; kc++) {
        __syncthreads();
#pragma unroll
        for (int i = 0; i < 4; i++) {
            int lin = tid + 256 * i;  // 0..1023
            int row = lin >> 4, f4c = lin & 15;
            in_lds[row * 17 + f4c] =
                ((const float4*)hseq)[((size_t)(r0 + row)) * 128 + kc * 16 + f4c];
        }
        __syncthreads();
#pragma unroll 2
        for (int k4 = 0; k4 < 16; k4++) {
            float4 w[4];
#pragma unroll
            for (int vi = 0; vi < 4; vi++)
                w[vi] = w4[(size_t)(vbase + vi) * 128 + kc * 16 + k4];
#pragma unroll
            for (int ri = 0; ri < 4; ri++) {
                float4 iv = in_lds[(ry * 4 + ri) * 17 + k4];
#pragma unroll
                for (int vi = 0; vi < 4; vi++) {
                    acc[ri][vi] += w[vi].x * iv.x + w[vi].y * iv.y +
                                   w[vi].z * iv.z + w[vi].w * iv.w;
                }
            }
        }
    }

    float pb[4];
#pragma unroll
    for (int vi = 0; vi < 4; vi++) pb[vi] = proj_b[vbase + vi];
#pragma unroll
    for (int ri = 0; ri < 4; ri++) {
        float s = 0.f;
#pragma unroll
        for (int vi = 0; vi < 4; vi++) s += __expf(acc[ri][vi] + pb[vi]);
        s += __shfl_xor(s, 1, 64);
        s += __shfl_xor(s, 2, 64);
        s += __shfl_xor(s, 4, 64);
        s += __shfl_xor(s, 8, 64);
        if (vx == 0) atomicAdd(&sumexp[r0 + ry * 4 + ri], s);
    }
}

// ---------------------------------------------------------------------------
// Final: nll = log(sumexp) - logit[label]; masked mean. grid(64), block(64)
// ---------------------------------------------------------------------------
__global__ void loss_kernel(const float* __restrict__ hseq,
                            const float* __restrict__ proj_w,
                            const float* __restrict__ proj_b,
                            const float* __restrict__ sumexp,
                            const int* __restrict__ seq_label,
                            float* __restrict__ out) {
    int b = blockIdx.x;
    int lane = threadIdx.x;
    float num = 0.f, den = 0.f;
    for (int t = 0; t < T; t++) {
        int label = seq_label[b * T + t];
        const float* hp = hseq + ((size_t)b * T + t) * 512;
        const float* wp = proj_w + (size_t)label * 512;
        float acc = 0.f;
#pragma unroll
        for (int i = 0; i < 8; i++) acc += hp[lane + 64 * i] * wp[lane + 64 * i];
        for (int off = 32; off > 0; off >>= 1) acc += __shfl_xor(acc, off, 64);
        if (lane == 0) {
            float nll = logf(sumexp[b * T + t]) - (acc + proj_b[label]);
            float mask = (label > 0) ? 1.f : 0.f;
            num += mask * nll;
            den += mask;
        }
    }
    if (lane == 0) {
        atomicAdd(out, (num / (den + 1e-6f)) * (1.f / 64.f));
    }
}

// ---------------------------------------------------------------------------
extern "C" void kernel_launch(void* const* d_in, const int* in_sizes, int n_in,
                              void* d_out, int out_size, void* d_ws, size_t ws_size,
                              hipStream_t stream) {
    const float* enc_h     = (const float*)d_in[0];
    const float* enc_out   = (const float*)d_in[1];
    // d_in[2] encoder_mask: unused by reference decode
    const int*   seq_label = (const int*)d_in[3];
    const int*   dec_in    = (const int*)d_in[4];
    const float* style     = (const float*)d_in[5];
    const float* W_e2d_w   = (const float*)d_in[6];
    const float* W_e2d_b   = (const float*)d_in[7];
    const float* attn_W    = (const float*)d_in[8];
    const float* emb_table = (const float*)d_in[9];
    const float* w_ih      = (const float*)d_in[10];
    const float* w_hh      = (const float*)d_in[11];
    const float* b_ih      = (const float*)d_in[12];
    const float* b_hh      = (const float*)d_in[13];
    const float* proj_w    = (const float*)d_in[14];
    const float* proj_b    = (const float*)d_in[15];
    float* out = (float*)d_out;

    // workspace layout (floats)
    float* h      = (float*)d_ws;        // 64*512
    float* c      = h + 64 * 512;        // 64*512
    float* ctx    = c + 64 * 512;        // 64*512
    float* part   = ctx + 64 * 512;      // 6*2048*64 = 786432
    float* hseq   = part + 786432;       // 64*21*512 = 688128
    float* sumexp = hseq + 688128;       // 1344

    hipMemsetAsync(sumexp, 0, 1344 * sizeof(float), stream);
    hipMemsetAsync(out, 0, sizeof(float), stream);

    h0_kernel<<<64, 256, 0, stream>>>(enc_h, style, W_e2d_w, W_e2d_b, h, c);

    for (int t = 0; t < T; t++) {
        attn_kernel<<<64, 256, 0, stream>>>(h, attn_W, enc_out, ctx);
        gates_kernel<<<64 * 6, 256, 0, stream>>>(ctx, h, emb_table, dec_in,
                                                 w_ih, w_hh, part, t);
        lstm_update_kernel<<<128, 256, 0, stream>>>(part, b_ih, b_hh, h, c, hseq, t);
    }

    proj_sumexp_kernel<<<dim3(500, 21), 256, 0, stream>>>(hseq, proj_w, proj_b, sumexp);
    loss_kernel<<<64, 64, 0, stream>>>(hseq, proj_w, proj_b, sumexp, seq_label, out);
}

// Round 2
// 2479.618 us; speedup vs baseline: 1.8160x; 1.8160x over previous
//
#include <hip/hip_runtime.h>
#include <hip/hip_bf16.h>
#include <math.h>

// Problem constants
#define B 64
#define S 64
#define T 21
#define ENC_D 512
#define HID 512
#define EMB 512
#define STYLE 128
#define VOCAB 32000

typedef __bf16 bf16x8 __attribute__((ext_vector_type(8)));
typedef float f32x4 __attribute__((ext_vector_type(4)));

__device__ __forceinline__ unsigned short f32_to_bf16_rne(float x) {
    union { float f; unsigned int u; } v;
    v.f = x;
    unsigned int u = v.u;
    unsigned int r = (u + 0x7FFFu + ((u >> 16) & 1u)) >> 16;
    return (unsigned short)r;
}

// ---------------------------------------------------------------------------
// Kernel A: h0 = concat(encode_hidden, style_emb[:,3,:]) @ W_e2d_w.T + b ; c0=0
// ---------------------------------------------------------------------------
__global__ void h0_kernel(const float* __restrict__ enc_h,
                          const float* __restrict__ style,
                          const float* __restrict__ W,
                          const float* __restrict__ bias,
                          float* __restrict__ h, float* __restrict__ c) {
    int b = blockIdx.x;
    int tid = threadIdx.x;
    __shared__ __attribute__((aligned(16))) float in[640];
    for (int i = tid; i < 512; i += 256) in[i] = enc_h[b * 512 + i];
    if (tid < 128) in[512 + tid] = style[b * 512 + 384 + tid];  // style[b][3][tid]
    __syncthreads();
    for (int j = tid; j < 512; j += 256) {
        const float4* w4 = (const float4*)(W + (size_t)j * 640);
        float acc = 0.f;
#pragma unroll 4
        for (int k4 = 0; k4 < 160; k4++) {
            float4 w = w4[k4];
            float4 iv = *(const float4*)(in + k4 * 4);
            acc += w.x * iv.x + w.y * iv.y + w.z * iv.z + w.w * iv.w;
        }
        h[b * 512 + j] = acc + bias[j];
        c[b * 512 + j] = 0.f;
    }
}

// ---------------------------------------------------------------------------
// proj_w fp32 -> bf16 conversion. 16.384M elements, 8 per thread.
// grid(8000), block(256)
// ---------------------------------------------------------------------------
__global__ void wconv_kernel(const float* __restrict__ w,
                             unsigned short* __restrict__ wbf) {
    size_t i = ((size_t)blockIdx.x * 256 + threadIdx.x) * 8;
    float4 a = *(const float4*)(w + i);
    float4 b = *(const float4*)(w + i + 4);
    ushort4 lo, hi;
    lo.x = f32_to_bf16_rne(a.x); lo.y = f32_to_bf16_rne(a.y);
    lo.z = f32_to_bf16_rne(a.z); lo.w = f32_to_bf16_rne(a.w);
    hi.x = f32_to_bf16_rne(b.x); hi.y = f32_to_bf16_rne(b.y);
    hi.z = f32_to_bf16_rne(b.z); hi.w = f32_to_bf16_rne(b.w);
    *(ushort4*)(wbf + i) = lo;
    *(ushort4*)(wbf + i + 4) = hi;
}

// ---------------------------------------------------------------------------
// Kernel B: attention for one step. grid(64), block(256)
// ---------------------------------------------------------------------------
__global__ void attn_kernel(const float* __restrict__ h,
                            const float* __restrict__ attn_W,
                            const float* __restrict__ enc_out,
                            float* __restrict__ ctx) {
    int b = blockIdx.x;
    int tid = threadIdx.x;
    __shared__ __attribute__((aligned(16))) float hbuf[512];
    __shared__ __attribute__((aligned(16))) float abuf[512];
    __shared__ float scp[4][64];
    __shared__ float sc[64];

    for (int i = tid; i < 512; i += 256) hbuf[i] = h[b * 512 + i];
    __syncthreads();

    {
        int d0 = tid, d1 = tid + 256;
        float acc0 = 0.f, acc1 = 0.f;
#pragma unroll 4
        for (int j = 0; j < 512; j++) {
            float hv = hbuf[j];
            acc0 += hv * attn_W[(size_t)j * 512 + d0];
            acc1 += hv * attn_W[(size_t)j * 512 + d1];
        }
        abuf[d0] = acc0;
        abuf[d1] = acc1;
    }
    __syncthreads();

    {
        int s = tid & 63, q = tid >> 6;
        const float4* e4 = (const float4*)(enc_out + ((size_t)b * 64 + s) * 512 + q * 128);
        const float4* a4 = (const float4*)(abuf + q * 128);
        float acc = 0.f;
#pragma unroll 8
        for (int k = 0; k < 32; k++) {
            float4 e = e4[k];
            float4 a = a4[k];
            acc += e.x * a.x + e.y * a.y + e.z * a.z + e.w * a.w;
        }
        scp[q][s] = acc;
    }
    __syncthreads();

    if (tid < 64) {
        float v = scp[0][tid] + scp[1][tid] + scp[2][tid] + scp[3][tid];
        float m = v;
        for (int off = 32; off > 0; off >>= 1) m = fmaxf(m, __shfl_xor(m, off, 64));
        float e = __expf(v - m);
        float ssum = e;
        for (int off = 32; off > 0; off >>= 1) ssum += __shfl_xor(ssum, off, 64);
        sc[tid] = e / ssum;
    }
    __syncthreads();

    {
        int d0 = tid, d1 = tid + 256;
        float acc0 = 0.f, acc1 = 0.f;
        const float* ep = enc_out + (size_t)b * 64 * 512;
#pragma unroll 4
        for (int s = 0; s < 64; s++) {
            float a = sc[s];
            acc0 += a * ep[(size_t)s * 512 + d0];
            acc1 += a * ep[(size_t)s * 512 + d1];
        }
        ctx[b * 512 + d0] = acc0;
        ctx[b * 512 + d1] = acc1;
    }
}

// ---------------------------------------------------------------------------
// Kernel C: gates partial GEMM. grid(64*6), block(256)
// ---------------------------------------------------------------------------
__global__ void gates_kernel(const float* __restrict__ ctx,
                             const float* __restrict__ h,
                             const float* __restrict__ emb_table,
                             const int* __restrict__ dec_in,
                             const float* __restrict__ w_ih,
                             const float* __restrict__ w_hh,
                             float* __restrict__ part, int t) {
    int jt = blockIdx.x & 63;
    int chunk = blockIdx.x >> 6;  // 0..5
    int seg = chunk >> 1;         // 0: ctx, 1: emb, 2: h
    int half = chunk & 1;         // k offset 0 / 256
    int tid = threadIdx.x;
    int b = tid & 63;
    int ty = tid >> 6;
    int j0 = jt * 32 + ty * 8;

    const float* src;
    if (seg == 0)      src = ctx + b * 512 + half * 256;
    else if (seg == 1) src = emb_table + (size_t)dec_in[b * T + t] * 512 + half * 256;
    else               src = h + b * 512 + half * 256;

    const float* wbase;
    size_t wstride;
    if (seg < 2) { wbase = w_ih + seg * 512 + half * 256; wstride = 1024; }
    else         { wbase = w_hh + half * 256;             wstride = 512; }

    float acc[8] = {0, 0, 0, 0, 0, 0, 0, 0};
    const float4* s4 = (const float4*)src;
#pragma unroll 4
    for (int k4 = 0; k4 < 64; k4++) {
        float4 iv = s4[k4];
#pragma unroll
        for (int jj = 0; jj < 8; jj++) {
            float4 w = *(const float4*)(wbase + (size_t)(j0 + jj) * wstride + k4 * 4);
            acc[jj] += w.x * iv.x + w.y * iv.y + w.z * iv.z + w.w * iv.w;
        }
    }
#pragma unroll
    for (int jj = 0; jj < 8; jj++) {
        part[((size_t)chunk * 2048 + (j0 + jj)) * 64 + b] = acc[jj];
    }
}

// ---------------------------------------------------------------------------
// Kernel D: reduce 6 partials, LSTM cell, write h, c, hseq (fp32 + bf16)
// grid(128), block(256)
// ---------------------------------------------------------------------------
__global__ void lstm_update_kernel(const float* __restrict__ part,
                                   const float* __restrict__ b_ih,
                                   const float* __restrict__ b_hh,
                                   float* __restrict__ h, float* __restrict__ c,
                                   float* __restrict__ hseq,
                                   unsigned short* __restrict__ hseqb, int t) {
    int g = blockIdx.x * 256 + threadIdx.x;  // 0..32767
    int b = g & 63;
    int u = g >> 6;  // 0..511
    float gate[4];
#pragma unroll
    for (int gi = 0; gi < 4; gi++) {
        int j = u + gi * 512;
        float s = b_ih[j] + b_hh[j];
#pragma unroll
        for (int cc = 0; cc < 6; cc++) s += part[((size_t)cc * 2048 + j) * 64 + b];
        gate[gi] = s;
    }
    float ig = 1.f / (1.f + __expf(-gate[0]));
    float fg = 1.f / (1.f + __expf(-gate[1]));
    float gg = tanhf(gate[2]);
    float og = 1.f / (1.f + __expf(-gate[3]));
    float cn = fg * c[b * 512 + u] + ig * gg;
    float hn = og * tanhf(cn);
    c[b * 512 + u] = cn;
    h[b * 512 + u] = hn;
    size_t idx = ((size_t)b * T + t) * 512 + u;
    hseq[idx] = hn;
    hseqb[idx] = f32_to_bf16_rne(hn);
}

// ---------------------------------------------------------------------------
// Projection + exp-sum via bf16 MFMA.
// C[m][n] = hseq[m][:] . proj_w[n][:]  (both K-major, K=512), M=1344, N=32000.
// grid(500): each block owns a 64-col vocab tile, loops over all 84 M-tiles
// of 16 rows. 4 waves/block, wave w takes cols [n0+16w, n0+16w+16).
// Per M-tile: 16 k-steps of mfma_f32_16x16x32_bf16, then exp + row-reduce;
// per-block row sums go to partial[blockIdx][1344] (no atomics).
// A-fragment: lane holds A[m0 + (lane&15)][ks*32 + (lane>>4)*8 + 0..7]
// B-fragment: lane holds W [n  + (lane&15)][same k]   (16B contiguous loads)
// C/D: col = lane&15, row = (lane>>4)*4 + reg.
// ---------------------------------------------------------------------------
__global__ void proj_mfma_kernel(const unsigned short* __restrict__ hseqb,
                                 const unsigned short* __restrict__ wbf,
                                 const float* __restrict__ proj_b,
                                 float* __restrict__ partial) {
    int tid = threadIdx.x;
    int w = tid >> 6;
    int lane = tid & 63;
    int col = lane & 15;
    int kq = lane >> 4;  // 0..3
    int n0 = blockIdx.x * 64;
    int n = n0 + w * 16 + col;

    float bias = proj_b[n];
    const unsigned short* wrow = wbf + (size_t)n * 512 + kq * 8;

    __shared__ float sums[4][16];

    for (int mt = 0; mt < 84; mt++) {
        int m0 = mt * 16;
        const unsigned short* arow = hseqb + (size_t)(m0 + col) * 512 + kq * 8;
        f32x4 acc = {0.f, 0.f, 0.f, 0.f};
#pragma unroll
        for (int ks = 0; ks < 16; ks++) {
            bf16x8 af = *reinterpret_cast<const bf16x8*>(arow + ks * 32);
            bf16x8 bf = *reinterpret_cast<const bf16x8*>(wrow + ks * 32);
            acc = __builtin_amdgcn_mfma_f32_16x16x32_bf16(af, bf, acc, 0, 0, 0);
        }
        // epilogue: e = exp(logit + bias); reduce over 16 cols (lanes)
#pragma unroll
        for (int reg = 0; reg < 4; reg++) {
            float e = __expf(acc[reg] + bias);
            e += __shfl_xor(e, 1, 64);
            e += __shfl_xor(e, 2, 64);
            e += __shfl_xor(e, 4, 64);
            e += __shfl_xor(e, 8, 64);
            if (col == 0) sums[w][kq * 4 + reg] = e;  // row = kq*4+reg
        }
        __syncthreads();
        if (tid < 16) {
            float s = sums[0][tid] + sums[1][tid] + sums[2][tid] + sums[3][tid];
            partial[(size_t)blockIdx.x * 1344 + m0 + tid] = s;
        }
        __syncthreads();
    }
}

// ---------------------------------------------------------------------------
// Reduce partial[500][1344] -> sumexp[1344]. grid(6), block(256)
// ---------------------------------------------------------------------------
__global__ void sumexp_reduce_kernel(const float* __restrict__ partial,
                                     float* __restrict__ sumexp) {
    int m = blockIdx.x * 256 + threadIdx.x;
    if (m >= 1344) return;
    float s = 0.f;
    for (int nb = 0; nb < 500; nb++) s += partial[(size_t)nb * 1344 + m];
    sumexp[m] = s;
}

// ---------------------------------------------------------------------------
// Final loss. grid(64), block(64)
// ---------------------------------------------------------------------------
__global__ void loss_kernel(const float* __restrict__ hseq,
                            const float* __restrict__ proj_w,
                            const float* __restrict__ proj_b,
                            const float* __restrict__ sumexp,
                            const int* __restrict__ seq_label,
                            float* __restrict__ out) {
    int b = blockIdx.x;
    int lane = threadIdx.x;
    float num = 0.f, den = 0.f;
    for (int t = 0; t < T; t++) {
        int label = seq_label[b * T + t];
        const float* hp = hseq + ((size_t)b * T + t) * 512;
        const float* wp = proj_w + (size_t)label * 512;
        float acc = 0.f;
#pragma unroll
        for (int i = 0; i < 8; i++) acc += hp[lane + 64 * i] * wp[lane + 64 * i];
        for (int off = 32; off > 0; off >>= 1) acc += __shfl_xor(acc, off, 64);
        if (lane == 0) {
            float nll = logf(sumexp[b * T + t]) - (acc + proj_b[label]);
            float mask = (label > 0) ? 1.f : 0.f;
            num += mask * nll;
            den += mask;
        }
    }
    if (lane == 0) {
        atomicAdd(out, (num / (den + 1e-6f)) * (1.f / 64.f));
    }
}

// ---------------------------------------------------------------------------
extern "C" void kernel_launch(void* const* d_in, const int* in_sizes, int n_in,
                              void* d_out, int out_size, void* d_ws, size_t ws_size,
                              hipStream_t stream) {
    const float* enc_h     = (const float*)d_in[0];
    const float* enc_out   = (const float*)d_in[1];
    const int*   seq_label = (const int*)d_in[3];
    const int*   dec_in    = (const int*)d_in[4];
    const float* style     = (const float*)d_in[5];
    const float* W_e2d_w   = (const float*)d_in[6];
    const float* W_e2d_b   = (const float*)d_in[7];
    const float* attn_W    = (const float*)d_in[8];
    const float* emb_table = (const float*)d_in[9];
    const float* w_ih      = (const float*)d_in[10];
    const float* w_hh      = (const float*)d_in[11];
    const float* b_ih      = (const float*)d_in[12];
    const float* b_hh      = (const float*)d_in[13];
    const float* proj_w    = (const float*)d_in[14];
    const float* proj_b    = (const float*)d_in[15];
    float* out = (float*)d_out;

    // workspace layout (float units)
    float* h      = (float*)d_ws;            // 32768
    float* c      = h + 32768;               // 32768
    float* ctx    = c + 32768;               // 32768
    float* part   = ctx + 32768;             // 786432
    float* hseq   = part + 786432;           // 688128
    float* sumexp = hseq + 688128;           // 1344
    float* partial = sumexp + 1344;          // 500*1344 = 672000
    unsigned short* hseqb = (unsigned short*)(partial + 672000);  // 688128 us
    unsigned short* wbf   = hseqb + 688128;  // 16384000 us

    hipMemsetAsync(out, 0, sizeof(float), stream);

    h0_kernel<<<64, 256, 0, stream>>>(enc_h, style, W_e2d_w, W_e2d_b, h, c);
    wconv_kernel<<<8000, 256, 0, stream>>>(proj_w, wbf);

    for (int t = 0; t < T; t++) {
        attn_kernel<<<64, 256, 0, stream>>>(h, attn_W, enc_out, ctx);
        gates_kernel<<<64 * 6, 256, 0, stream>>>(ctx, h, emb_table, dec_in,
                                                 w_ih, w_hh, part, t);
        lstm_update_kernel<<<128, 256, 0, stream>>>(part, b_ih, b_hh, h, c,
                                                    hseq, hseqb, t);
    }

    proj_mfma_kernel<<<500, 256, 0, stream>>>(hseqb, wbf, proj_b, partial);
    sumexp_reduce_kernel<<<6, 256, 0, stream>>>(partial, sumexp);
    loss_kernel<<<64, 64, 0, stream>>>(hseq, proj_w, proj_b, sumexp, seq_label, out);
}